// Round 2
// baseline (663.487 us; speedup 1.0000x reference)
//
#include <hip/hip_runtime.h>

#define TSTEPS 1024
#define CH 4               // chains per block (cols 0..3 of the MFMA tile)

typedef _Float16 half8  __attribute__((ext_vector_type(8)));
typedef float    f32x4  __attribute__((ext_vector_type(4)));

#define MFMA16(A_, B_, C_) __builtin_amdgcn_mfma_f32_16x16x32_f16((A_), (B_), (C_), 0, 0, 0)

__device__ __forceinline__ float fast_rcp(float x) { return __builtin_amdgcn_rcpf(x); }
__device__ __forceinline__ float fast_exp2(float x) {
#if __has_builtin(__builtin_amdgcn_exp2f)
    return __builtin_amdgcn_exp2f(x);
#else
    return exp2f(x);
#endif
}

// load 8 consecutive fp32, scale, convert to packed f16 MFMA fragment
__device__ __forceinline__ half8 load_w8s(const float* p, float s) {
    const float4 a = ((const float4*)p)[0];
    const float4 b = ((const float4*)p)[1];
    half8 r;
    r[0] = (_Float16)(s * a.x); r[1] = (_Float16)(s * a.y);
    r[2] = (_Float16)(s * a.z); r[3] = (_Float16)(s * a.w);
    r[4] = (_Float16)(s * b.x); r[5] = (_Float16)(s * b.y);
    r[6] = (_Float16)(s * b.z); r[7] = (_Float16)(s * b.w);
    return r;
}

// R15: MERGED WAVES. R14 post-mortem: bpermute redistribution flooded the
// per-CU DS pipe (12-16 full-wave crossbar ops/tick vs 6 scratch ops) ->
// +25%. Reverted to R13 scratch. R13's real limiter: 6 unequal waves on 4
// SIMDs -- two SIMDs host a lone GRU1 wave (latency exposed), and the
// barrier waits for the slowest (GRU2, 9 MFMA 3-deep). GRU1(t) and
// GRU2(t-1) are independent within a tick (GRU2 reads h1(t-1), h2(t-2),
// both visible), so fuse them into the SAME 4 waves:
//   wave w: GRU1 unit-tile w*16..w*16+15 (unchanged) + GRU2 units
//   w*8..w*8+7 (16x16 MFMA tile, rows mirrored via nl&7; duplicate rows
//   computed and discarded -- MFMA pipe is 17% busy, waste is free).
// GRU2's MFMAs sit in program order INSIDE GRU1's scratch round-trip,
// hiding it with guaranteed intra-wave ILP instead of lucky co-residency.
// B0/B1 (h1(t-1) fragments, same parity for both GRUs) loaded ONCE.
// 4 identical waves -> no barrier skew; 256 threads.
// MFMA layouts (m89/m120-verified): A[m=lane&15][k=quad*8+j],
// B[k=quad*8+j][n=lane&15], C/D: col(n)=lane&15, row(m)=quad*4+reg.
// h-parity (R8 scheme): at tick t, h1(t-1) in s_h1[(t+1)&1]; GRU2 reads
// h2(t-2) from s_h2[t&1], writes h2(t-1) to s_h2[(t+1)&1].
// h-state cols CH..15 stay zero forever (init once, never rewritten).
__global__ __launch_bounds__(256, 1)
void gru2_encoder(const float* __restrict__ x,
                  const float* __restrict__ W_ih1,
                  const float* __restrict__ W_hh1,
                  const float* __restrict__ b_ih1,
                  const float* __restrict__ b_hh1,
                  const float* __restrict__ W_ih2,
                  const float* __restrict__ W_hh2,
                  const float* __restrict__ b_ih2,
                  const float* __restrict__ b_hh2,
                  float* __restrict__ out)
{
    const int blk  = blockIdx.x;    // 256 blocks, CH chains each
    const int tid  = threadIdx.x;   // 256
    const int lane = tid & 63;
    const int wid  = tid >> 6;      // 0..3
    const int nl   = lane & 15;     // chain col (0..CH-1 real, rest dead)
    const int quad = lane >> 4;     // 0..3
    const int uu   = lane >> 2;     // redistributed unit-within-tile (0..15)
    const int cc   = lane & 3;      // redistributed chain (0..3)
    const int chain0 = blk * CH;

    const float SNEG = -1.44269504f;       // -log2(e)
    const float SP2  =  2.88539008f;       // 2*log2(e)

    __shared__ __align__(16) _Float16 s_h1[2][16][72];   // [par][chain][unit64+pad]
    __shared__ __align__(16) _Float16 s_h2[2][16][40];   // [par][chain][unit32+pad]
    __shared__ __align__(16) _Float16 s_x[TSTEPS][4];    // x f16, [t][chain]
    // per-wave preact scratch: planes 0..2 GRU1 (r,z,n), 3..6 GRU2 (r,z,nx,nh)
    __shared__ __align__(16) float sc[4][7][CH][20];

    // ---- one-time staging
    for (int idx = tid; idx < 4 * TSTEPS; idx += 256) {
        const int m = idx >> 10, t = idx & (TSTEPS - 1);
        s_x[t][m] = (_Float16)x[(size_t)(chain0 + m) * TSTEPS + t];
    }
    {
        _Float16* p1 = &s_h1[0][0][0];
        for (int idx = tid; idx < 2 * 16 * 72; idx += 256) p1[idx] = (_Float16)0.0f;
        _Float16* p2 = &s_h2[0][0][0];
        for (int idx = tid; idx < 2 * 16 * 40; idx += 256) p2[idx] = (_Float16)0.0f;
    }
    __syncthreads();

    // ================= GRU1 constants: unit-tile U0 = wid*16 =================
    const int U0 = wid * 16;
    const int ur = U0 + nl;
    const half8 aWr0 = load_w8s(W_hh1 + (size_t)(ur)       * 64 + quad * 8,      SNEG);
    const half8 aWr1 = load_w8s(W_hh1 + (size_t)(ur)       * 64 + 32 + quad * 8, SNEG);
    const half8 aWz0 = load_w8s(W_hh1 + (size_t)(64 + ur)  * 64 + quad * 8,      SNEG);
    const half8 aWz1 = load_w8s(W_hh1 + (size_t)(64 + ur)  * 64 + 32 + quad * 8, SNEG);
    const half8 aWn0 = load_w8s(W_hh1 + (size_t)(128 + ur) * 64 + quad * 8,      SP2);
    const half8 aWn1 = load_w8s(W_hh1 + (size_t)(128 + ur) * 64 + 32 + quad * 8, SP2);
    const int u4 = U0 + quad * 4;
    const float4 bir1 = *(const float4*)(b_ih1 + u4);
    const float4 bhr1 = *(const float4*)(b_hh1 + u4);
    const float4 biz1 = *(const float4*)(b_ih1 + 64 + u4);
    const float4 bhz1 = *(const float4*)(b_hh1 + 64 + u4);
    const float4 bhn1 = *(const float4*)(b_hh1 + 128 + u4);
    const f32x4 Cr = {SNEG*(bir1.x+bhr1.x), SNEG*(bir1.y+bhr1.y), SNEG*(bir1.z+bhr1.z), SNEG*(bir1.w+bhr1.w)};
    const f32x4 Cz = {SNEG*(biz1.x+bhz1.x), SNEG*(biz1.y+bhz1.y), SNEG*(biz1.z+bhz1.z), SNEG*(biz1.w+bhz1.w)};
    const f32x4 Cn = {SP2*bhn1.x, SP2*bhn1.y, SP2*bhn1.z, SP2*bhn1.w};
    // x-path scalars for this lane's ONE redistributed unit (U0+uu)
    const int ru = U0 + uu;
    const float twr = SNEG * W_ih1[ru];
    const float twz = SNEG * W_ih1[64 + ru];
    const float twn = SP2  * W_ih1[128 + ru];
    const float tbn = SP2  * b_ih1[128 + ru];

    // ================= GRU2 constants: units w8..w8+7 (rows mirrored) ========
    const int w8  = wid * 8;
    const int vr2 = w8 + (nl & 7);          // mirror rows 8..15 onto 0..7
    const half8 AiR0 = load_w8s(W_ih2 + (size_t)(vr2)      * 64 + quad * 8,      SNEG);
    const half8 AiR1 = load_w8s(W_ih2 + (size_t)(vr2)      * 64 + 32 + quad * 8, SNEG);
    const half8 AiZ0 = load_w8s(W_ih2 + (size_t)(32 + vr2) * 64 + quad * 8,      SNEG);
    const half8 AiZ1 = load_w8s(W_ih2 + (size_t)(32 + vr2) * 64 + 32 + quad * 8, SNEG);
    const half8 AiN0 = load_w8s(W_ih2 + (size_t)(64 + vr2) * 64 + quad * 8,      SP2);
    const half8 AiN1 = load_w8s(W_ih2 + (size_t)(64 + vr2) * 64 + 32 + quad * 8, SP2);
    const half8 AhR  = load_w8s(W_hh2 + (size_t)(vr2)      * 32 + quad * 8,      SNEG);
    const half8 AhZ  = load_w8s(W_hh2 + (size_t)(32 + vr2) * 32 + quad * 8,      SNEG);
    const half8 AhN  = load_w8s(W_hh2 + (size_t)(64 + vr2) * 32 + quad * 8,      SP2);
    // C rows m=quad*4+reg, mirrored: real row = w8 + ((quad&1)*4) + reg
    const int v4 = w8 + (quad & 1) * 4;
    const float4 bir2 = *(const float4*)(b_ih2 + v4);
    const float4 bhr2 = *(const float4*)(b_hh2 + v4);
    const float4 biz2 = *(const float4*)(b_ih2 + 32 + v4);
    const float4 bhz2 = *(const float4*)(b_hh2 + 32 + v4);
    const float4 bin2 = *(const float4*)(b_ih2 + 64 + v4);
    const float4 bhn2 = *(const float4*)(b_hh2 + 64 + v4);
    const f32x4 Gr  = {SNEG*(bir2.x+bhr2.x), SNEG*(bir2.y+bhr2.y), SNEG*(bir2.z+bhr2.z), SNEG*(bir2.w+bhr2.w)};
    const f32x4 Gz  = {SNEG*(biz2.x+bhz2.x), SNEG*(biz2.y+bhz2.y), SNEG*(biz2.z+bhz2.z), SNEG*(biz2.w+bhz2.w)};
    const f32x4 Gnx = {SP2*bin2.x, SP2*bin2.y, SP2*bin2.z, SP2*bin2.w};
    const f32x4 Gnh = {SP2*bhn2.x, SP2*bhn2.y, SP2*bhn2.z, SP2*bhn2.w};

    float h1s = 0.0f;   // h1[unit U0+uu][chain cc]
    float h2s = 0.0f;   // h2[unit w8+(lane>>2)][chain cc], lanes<32 only

    for (int t = 0; t <= TSTEPS; ++t) {
        const int pr = (t + 1) & 1;   // parity of h1(t-1) -- shared by GRU1 & GRU2
        const half8 B0 = *(const half8*)&s_h1[pr][nl][quad * 8];
        const half8 B1 = *(const half8*)&s_h1[pr][nl][32 + quad * 8];

        // ---- GRU1 MFMA + scratch publish
        if (t < TSTEPS) {
            f32x4 aR = MFMA16(aWr0, B0, Cr); aR = MFMA16(aWr1, B1, aR);
            f32x4 aZ = MFMA16(aWz0, B0, Cz); aZ = MFMA16(aWz1, B1, aZ);
            f32x4 aN = MFMA16(aWn0, B0, Cn); aN = MFMA16(aWn1, B1, aN);
            if (nl < CH) {
                *(f32x4*)&sc[wid][0][nl][quad * 4] = aR;
                *(f32x4*)&sc[wid][1][nl][quad * 4] = aZ;
                *(f32x4*)&sc[wid][2][nl][quad * 4] = aN;
            }
        }
        // ---- GRU2 MFMA + scratch publish (fills GRU1's scratch round-trip)
        if (t >= 1) {
            const half8 Bh = *(const half8*)&s_h2[t & 1][nl][quad * 8];   // h2(t-2)
            f32x4 aR = MFMA16(AiR0, B0, Gr);  aR = MFMA16(AiR1, B1, aR);
            aR = MFMA16(AhR, Bh, aR);
            f32x4 aZ = MFMA16(AiZ0, B0, Gz);  aZ = MFMA16(AiZ1, B1, aZ);
            aZ = MFMA16(AhZ, Bh, aZ);
            f32x4 aNx = MFMA16(AiN0, B0, Gnx); aNx = MFMA16(AiN1, B1, aNx);
            f32x4 aNh = MFMA16(AhN, Bh, Gnh);
            if (nl < CH) {
                *(f32x4*)&sc[wid][3][nl][quad * 4] = aR;
                *(f32x4*)&sc[wid][4][nl][quad * 4] = aZ;
                *(f32x4*)&sc[wid][5][nl][quad * 4] = aNx;
                *(f32x4*)&sc[wid][6][nl][quad * 4] = aNh;
            }
        }
        // ---- GRU1 gate math (1 triple/lane, 64 lanes)
        if (t < TSTEPS) {
            const float pR = sc[wid][0][cc][uu];
            const float pZ = sc[wid][1][cc][uu];
            const float pN = sc[wid][2][cc][uu];
            const float xv = (float)s_x[t][cc];
            const float ea = fast_exp2(fmaf(twr, xv, pR));     // e^{-ar}
            const float eb = fast_exp2(fmaf(twz, xv, pZ));     // e^{-az}
            const float d1 = 1.0f + ea, d2 = 1.0f + eb;
            const float inv = fast_rcp(d1 * d2);
            const float r = d2 * inv, z = d1 * inv;
            const float nx = fmaf(twn, xv, tbn);
            const float ec = fast_exp2(fmaf(r, pN, nx));       // e^{2an}
            const float nn = fmaf(-2.0f, fast_rcp(ec + 1.0f), 1.0f);
            h1s = nn + z * (h1s - nn);
            s_h1[t & 1][cc][ru] = (_Float16)h1s;               // cols>=CH untouched (stay 0)
        }
        // ---- GRU2 gate math (1 triple/lane, lanes<32: units w8..w8+7)
        if (t >= 1 && lane < 32) {
            const int u2 = lane >> 2;   // 0..7
            const float pR  = sc[wid][3][cc][u2];
            const float pZ  = sc[wid][4][cc][u2];
            const float pNx = sc[wid][5][cc][u2];
            const float pNh = sc[wid][6][cc][u2];
            const float ea = fast_exp2(pR);
            const float eb = fast_exp2(pZ);
            const float d1 = 1.0f + ea, d2 = 1.0f + eb;
            const float inv = fast_rcp(d1 * d2);
            const float r2 = d2 * inv, z2 = d1 * inv;
            const float ec = fast_exp2(fmaf(r2, pNh, pNx));
            const float n2 = fmaf(-2.0f, fast_rcp(ec + 1.0f), 1.0f);
            h2s = n2 + z2 * (h2s - n2);
            s_h2[(t + 1) & 1][cc][w8 + u2] = (_Float16)h2s;    // h2(t-1)
        }
        __syncthreads();
    }

    // lanes<32 hold h2 for (unit w8+(lane>>2), chain cc)
    if (lane < 32) {
        out[(size_t)(chain0 + cc) * 32 + w8 + (lane >> 2)] = h2s;
    }
}

extern "C" void kernel_launch(void* const* d_in, const int* in_sizes, int n_in,
                              void* d_out, int out_size, void* d_ws, size_t ws_size,
                              hipStream_t stream) {
    const float* x     = (const float*)d_in[0];
    const float* W_ih1 = (const float*)d_in[1];
    const float* W_hh1 = (const float*)d_in[2];
    const float* b_ih1 = (const float*)d_in[3];
    const float* b_hh1 = (const float*)d_in[4];
    const float* W_ih2 = (const float*)d_in[5];
    const float* W_hh2 = (const float*)d_in[6];
    const float* b_ih2 = (const float*)d_in[7];
    const float* b_hh2 = (const float*)d_in[8];
    float* out = (float*)d_out;

    gru2_encoder<<<dim3(1024 / CH), dim3(256), 0, stream>>>(
        x, W_ih1, W_hh1, b_ih1, b_hh1, W_ih2, W_hh2, b_ih2, b_hh2, out);
}

// Round 3
// 555.854 us; speedup vs baseline: 1.1936x; 1.1936x over previous
//
#include <hip/hip_runtime.h>

#define TSTEPS 1024
#define CH 16              // chains per block = full MFMA m-dim (all rows real)

typedef _Float16 half8  __attribute__((ext_vector_type(8)));
typedef _Float16 half4v __attribute__((ext_vector_type(4)));
typedef float    f32x4  __attribute__((ext_vector_type(4)));

#define MFMA16(A_, B_, C_) __builtin_amdgcn_mfma_f32_16x16x32_f16((A_), (B_), (C_), 0, 0, 0)

__device__ __forceinline__ float fast_rcp(float x) { return __builtin_amdgcn_rcpf(x); }
__device__ __forceinline__ float fast_exp2(float x) {
#if __has_builtin(__builtin_amdgcn_exp2f)
    return __builtin_amdgcn_exp2f(x);
#else
    return exp2f(x);
#endif
}

// load 8 consecutive fp32, scale, convert to packed f16 MFMA fragment
__device__ __forceinline__ half8 load_w8s(const float* p, float s) {
    const float4 a = ((const float4*)p)[0];
    const float4 b = ((const float4*)p)[1];
    half8 r;
    r[0] = (_Float16)(s * a.x); r[1] = (_Float16)(s * a.y);
    r[2] = (_Float16)(s * a.z); r[3] = (_Float16)(s * a.w);
    r[4] = (_Float16)(s * b.x); r[5] = (_Float16)(s * b.y);
    r[6] = (_Float16)(s * b.z); r[7] = (_Float16)(s * b.w);
    return r;
}

// R16: OPERAND-SWAPPED MFMA, CH=16. R15 post-mortem: MFMA 16x16x32 costs
// ~19.4cy/SIMD (m06-derived), so concentrating 13 of them on one wave
// serialized the tick; R13's real structure: 42 MFMA tiles/tick serving
// only 4 chains (12/16 cols dead) + a preact-redistribution LDS round-trip
// (~180cy serial) because C rows were units.
// Fix: D = A*B with A = h (m-rows = 16 CHAINS, all real), B = weights
// (n-cols = units). A/B per-lane layouts are mirrors (lane&15 = non-k dim,
// quad*8+j = k), so R13's fragments are reused verbatim -- only the MFMA
// argument order swaps and C transposes to [chain][unit]:
//   - same 42 MFMAs now serve 16 chains (4x amortization, grid = 64)
//   - C/D row(chain)=quad*4+reg, col(unit)=lane&15: each lane holds r,z,n
//     preacts of the SAME (chain,unit) in registers -> gate math is
//     IN-REGISTER, the sc scratch round-trip is DELETED.
//   - cost: 4 gate triples/lane (one per C-reg chain), independent ->
//     issue-bound, replaces the serial RT on the critical path.
// Waves: 0..3 GRU1 (unit-tile j=wid: units j*16+nl, 6 MFMA + 4 triples);
// 4..5 GRU2 (units w2*16+nl, one step behind, 9 MFMA + 4 triples).
// One __syncthreads per tick; R8 parity scheme unchanged: at tick t,
// h1(t-1) in s_h1[(t+1)&1]; GRU2 reads h2(t-2) from s_h2[t&1], writes
// h2(t-1) to s_h2[(t+1)&1]. exp2 pre-scaled gate math (R10-validated).
__global__ __launch_bounds__(384, 1)
void gru2_encoder(const float* __restrict__ x,
                  const float* __restrict__ W_ih1,
                  const float* __restrict__ W_hh1,
                  const float* __restrict__ b_ih1,
                  const float* __restrict__ b_hh1,
                  const float* __restrict__ W_ih2,
                  const float* __restrict__ W_hh2,
                  const float* __restrict__ b_ih2,
                  const float* __restrict__ b_hh2,
                  float* __restrict__ out)
{
    const int blk  = blockIdx.x;    // 64 blocks, 16 chains each
    const int tid  = threadIdx.x;   // 384
    const int lane = tid & 63;
    const int wid  = tid >> 6;      // 0..5
    const int nl   = lane & 15;     // MFMA non-k lane index
    const int quad = lane >> 4;     // 0..3
    const int chain0 = blk * CH;

    const float SNEG = -1.44269504f;       // -log2(e)
    const float SP2  =  2.88539008f;       // 2*log2(e)

    __shared__ __align__(16) _Float16 s_h1[2][16][72];   // [par][chain][unit64+pad]
    __shared__ __align__(16) _Float16 s_h2[2][16][40];   // [par][chain][unit32+pad]
    __shared__ __align__(16) _Float16 s_x[TSTEPS][16];   // x f16, [t][chain] (ALL 16 real)

    // ---- one-time staging: 16 chains of x (coalesced along t)
    for (int idx = tid; idx < 16 * TSTEPS; idx += 384) {
        const int m = idx >> 10, t = idx & (TSTEPS - 1);
        s_x[t][m] = (_Float16)x[(size_t)(chain0 + m) * TSTEPS + t];
    }
    {
        _Float16* p1 = &s_h1[0][0][0];
        for (int idx = tid; idx < 2 * 16 * 72; idx += 384) p1[idx] = (_Float16)0.0f;
        _Float16* p2 = &s_h2[0][0][0];
        for (int idx = tid; idx < 2 * 16 * 40; idx += 384) p2[idx] = (_Float16)0.0f;
    }
    __syncthreads();

    if (wid < 4) {
        // ================= GRU1, unit-tile j=wid: units j*16+nl =================
        const int un = wid * 16 + nl;        // this lane's output unit (n-col)
        // weights as B operand: B[k=quad*8+jj][n=nl] = W_hh1[un][k] (pre-scaled)
        const half8 Br0 = load_w8s(W_hh1 + (size_t)(un)        * 64 + quad * 8,      SNEG);
        const half8 Br1 = load_w8s(W_hh1 + (size_t)(un)        * 64 + 32 + quad * 8, SNEG);
        const half8 Bz0 = load_w8s(W_hh1 + (size_t)(64 + un)   * 64 + quad * 8,      SNEG);
        const half8 Bz1 = load_w8s(W_hh1 + (size_t)(64 + un)   * 64 + 32 + quad * 8, SNEG);
        const half8 Bn0 = load_w8s(W_hh1 + (size_t)(128 + un)  * 64 + quad * 8,      SP2);
        const half8 Bn1 = load_w8s(W_hh1 + (size_t)(128 + un)  * 64 + 32 + quad * 8, SP2);
        // bias depends on unit (col) only -> splat across the 4 C rows (chains)
        const float cr = SNEG * (b_ih1[un] + b_hh1[un]);
        const float cz = SNEG * (b_ih1[64 + un] + b_hh1[64 + un]);
        const float cn = SP2 * b_hh1[128 + un];
        const f32x4 Cr = {cr, cr, cr, cr};
        const f32x4 Cz = {cz, cz, cz, cz};
        const f32x4 Cn = {cn, cn, cn, cn};
        // x-path scalars for this lane's unit
        const float twr = SNEG * W_ih1[un];
        const float twz = SNEG * W_ih1[64 + un];
        const float twn = SP2  * W_ih1[128 + un];
        const float tbn = SP2  * b_ih1[128 + un];

        // h1 state for chains quad*4+0..3, unit un (static-indexed registers)
        float h10 = 0.0f, h11 = 0.0f, h12 = 0.0f, h13 = 0.0f;

        for (int t = 0; t <= TSTEPS; ++t) {
            if (t < TSTEPS) {
                const int pr = (t + 1) & 1;
                // A operand = h1(t-1): A[m=nl=chain][k=quad*8+jj]
                const half8 A0 = *(const half8*)&s_h1[pr][nl][quad * 8];
                const half8 A1 = *(const half8*)&s_h1[pr][nl][32 + quad * 8];
                f32x4 aR = MFMA16(A0, Br0, Cr); aR = MFMA16(A1, Br1, aR);
                f32x4 aZ = MFMA16(A0, Bz0, Cz); aZ = MFMA16(A1, Bz1, aZ);
                f32x4 aN = MFMA16(A0, Bn0, Cn); aN = MFMA16(A1, Bn1, aN);
                // x for this lane's 4 chains (quad*4..quad*4+3): one b64 read
                const half4v xh = *(const half4v*)&s_x[t][quad * 4];
                #pragma unroll
                for (int r = 0; r < 4; ++r) {
                    const float xv = (float)xh[r];
                    const float ea = fast_exp2(fmaf(twr, xv, aR[r]));   // e^{-ar}
                    const float eb = fast_exp2(fmaf(twz, xv, aZ[r]));   // e^{-az}
                    const float d1 = 1.0f + ea, d2 = 1.0f + eb;
                    const float inv = fast_rcp(d1 * d2);
                    const float rg = d2 * inv, zg = d1 * inv;
                    const float nx = fmaf(twn, xv, tbn);
                    const float ec = fast_exp2(fmaf(rg, aN[r], nx));    // e^{2an}
                    const float nn = fmaf(-2.0f, fast_rcp(ec + 1.0f), 1.0f);
                    float h = (r == 0) ? h10 : (r == 1) ? h11 : (r == 2) ? h12 : h13;
                    h = nn + zg * (h - nn);
                    if (r == 0) h10 = h; else if (r == 1) h11 = h;
                    else if (r == 2) h12 = h; else h13 = h;
                    s_h1[t & 1][quad * 4 + r][un] = (_Float16)h;
                }
            }
            __syncthreads();
        }
    } else {
        // ================= GRU2, unit-tile w2=wid-4: units w2*16+nl, one step behind
        const int w2 = wid - 4;
        const int vn = w2 * 16 + nl;         // this lane's output unit (n-col)
        const half8 BiR0 = load_w8s(W_ih2 + (size_t)(vn)      * 64 + quad * 8,      SNEG);
        const half8 BiR1 = load_w8s(W_ih2 + (size_t)(vn)      * 64 + 32 + quad * 8, SNEG);
        const half8 BiZ0 = load_w8s(W_ih2 + (size_t)(32 + vn) * 64 + quad * 8,      SNEG);
        const half8 BiZ1 = load_w8s(W_ih2 + (size_t)(32 + vn) * 64 + 32 + quad * 8, SNEG);
        const half8 BiN0 = load_w8s(W_ih2 + (size_t)(64 + vn) * 64 + quad * 8,      SP2);
        const half8 BiN1 = load_w8s(W_ih2 + (size_t)(64 + vn) * 64 + 32 + quad * 8, SP2);
        const half8 BhR  = load_w8s(W_hh2 + (size_t)(vn)      * 32 + quad * 8,      SNEG);
        const half8 BhZ  = load_w8s(W_hh2 + (size_t)(32 + vn) * 32 + quad * 8,      SNEG);
        const half8 BhN  = load_w8s(W_hh2 + (size_t)(64 + vn) * 32 + quad * 8,      SP2);
        const float gr  = SNEG * (b_ih2[vn] + b_hh2[vn]);
        const float gz  = SNEG * (b_ih2[32 + vn] + b_hh2[32 + vn]);
        const float gnx = SP2 * b_ih2[64 + vn];
        const float gnh = SP2 * b_hh2[64 + vn];
        const f32x4 Gr  = {gr, gr, gr, gr};
        const f32x4 Gz  = {gz, gz, gz, gz};
        const f32x4 Gnx = {gnx, gnx, gnx, gnx};
        const f32x4 Gnh = {gnh, gnh, gnh, gnh};

        float h20 = 0.0f, h21 = 0.0f, h22 = 0.0f, h23 = 0.0f;

        for (int t = 0; t <= TSTEPS; ++t) {
            if (t >= 1) {
                const int pA = (t + 1) & 1;            // parity of h1(t-1)
                const half8 A0 = *(const half8*)&s_h1[pA][nl][quad * 8];
                const half8 A1 = *(const half8*)&s_h1[pA][nl][32 + quad * 8];
                const half8 Ah = *(const half8*)&s_h2[t & 1][nl][quad * 8];   // h2(t-2)
                f32x4 aR = MFMA16(A0, BiR0, Gr);  aR = MFMA16(A1, BiR1, aR);
                aR = MFMA16(Ah, BhR, aR);
                f32x4 aZ = MFMA16(A0, BiZ0, Gz);  aZ = MFMA16(A1, BiZ1, aZ);
                aZ = MFMA16(Ah, BhZ, aZ);
                f32x4 aNx = MFMA16(A0, BiN0, Gnx); aNx = MFMA16(A1, BiN1, aNx);
                f32x4 aNh = MFMA16(Ah, BhN, Gnh);
                #pragma unroll
                for (int r = 0; r < 4; ++r) {
                    const float ea = fast_exp2(aR[r]);
                    const float eb = fast_exp2(aZ[r]);
                    const float d1 = 1.0f + ea, d2 = 1.0f + eb;
                    const float inv = fast_rcp(d1 * d2);
                    const float rg = d2 * inv, zg = d1 * inv;
                    const float ec = fast_exp2(fmaf(rg, aNh[r], aNx[r]));
                    const float n2 = fmaf(-2.0f, fast_rcp(ec + 1.0f), 1.0f);
                    float h = (r == 0) ? h20 : (r == 1) ? h21 : (r == 2) ? h22 : h23;
                    h = n2 + zg * (h - n2);
                    if (r == 0) h20 = h; else if (r == 1) h21 = h;
                    else if (r == 2) h22 = h; else h23 = h;
                    s_h2[(t + 1) & 1][quad * 4 + r][vn] = (_Float16)h;   // h2(t-1)
                }
            }
            __syncthreads();
        }

        // lane holds h2 for (chains quad*4+0..3, unit vn)
        out[(size_t)(chain0 + quad * 4 + 0) * 32 + vn] = h20;
        out[(size_t)(chain0 + quad * 4 + 1) * 32 + vn] = h21;
        out[(size_t)(chain0 + quad * 4 + 2) * 32 + vn] = h22;
        out[(size_t)(chain0 + quad * 4 + 3) * 32 + vn] = h23;
    }
}

extern "C" void kernel_launch(void* const* d_in, const int* in_sizes, int n_in,
                              void* d_out, int out_size, void* d_ws, size_t ws_size,
                              hipStream_t stream) {
    const float* x     = (const float*)d_in[0];
    const float* W_ih1 = (const float*)d_in[1];
    const float* W_hh1 = (const float*)d_in[2];
    const float* b_ih1 = (const float*)d_in[3];
    const float* b_hh1 = (const float*)d_in[4];
    const float* W_ih2 = (const float*)d_in[5];
    const float* W_hh2 = (const float*)d_in[6];
    const float* b_ih2 = (const float*)d_in[7];
    const float* b_hh2 = (const float*)d_in[8];
    float* out = (float*)d_out;

    gru2_encoder<<<dim3(1024 / CH), dim3(384), 0, stream>>>(
        x, W_ih1, W_hh1, b_ih1, b_hh1, W_ih2, W_hh2, b_ih2, b_hh2, out);
}

// Round 4
// 311.726 us; speedup vs baseline: 2.1284x; 1.7832x over previous
//
#include <hip/hip_runtime.h>

#define TSTEPS 1024
#define CH 4               // chains per block; replicated 4x across MFMA m-rows

typedef _Float16 half8  __attribute__((ext_vector_type(8)));
typedef float    f32x4  __attribute__((ext_vector_type(4)));

#define MFMA16(A_, B_, C_) __builtin_amdgcn_mfma_f32_16x16x32_f16((A_), (B_), (C_), 0, 0, 0)

__device__ __forceinline__ float fast_rcp(float x) { return __builtin_amdgcn_rcpf(x); }
__device__ __forceinline__ float fast_exp2(float x) {
#if __has_builtin(__builtin_amdgcn_exp2f)
    return __builtin_amdgcn_exp2f(x);
#else
    return exp2f(x);
#endif
}

// load 8 consecutive fp32, scale, convert to packed f16 MFMA fragment
__device__ __forceinline__ half8 load_w8s(const float* p, float s) {
    const float4 a = ((const float4*)p)[0];
    const float4 b = ((const float4*)p)[1];
    half8 r;
    r[0] = (_Float16)(s * a.x); r[1] = (_Float16)(s * a.y);
    r[2] = (_Float16)(s * a.z); r[3] = (_Float16)(s * a.w);
    r[4] = (_Float16)(s * b.x); r[5] = (_Float16)(s * b.y);
    r[6] = (_Float16)(s * b.z); r[7] = (_Float16)(s * b.w);
    return r;
}

// R17: OPERAND-SWAP at CH=4 via ROW-REPLICATED A. R16 post-mortem: swap's
// in-register preacts are real (bank conflicts 2.6e7->3.9e6) but CH=16
// meant 64 blocks (25% of CUs) and 4 gate-triples/lane (~256cy VALU/wave)
// -> tick 1164cy, net loss. This round keeps R13's shape (256 blocks x 4
// chains, 6 waves, 1 triple/lane) and imports the swap: the A operand
// replicates each chain across 4 m-rows -- lane loads A[m=nl] =
// h1[chain nl>>2][k]. C/D layout (row=quad*4+reg) then gives each lane 4
// IDENTICAL copies of (chain=quad, unit=nl)'s preact in its C-regs; use
// acc[0], discard the rest. Result: R13's triple economics with preacts
// in registers -- the sc scratch + lgkm drain + ~180cy serial round-trip
// deleted, no bpermute, no extra DS ops.
//   waves 0..3: GRU1 unit-tile wid (units wid*16+nl): 6 MFMA + 1 triple.
//   waves 4..5: GRU2 (units (wid-4)*16+nl), ONE STEP BEHIND: 9 MFMA + 1.
// LDS strides padded for uniform 2-way (free, m136) access: h1 stride 80
// (c*40+q*4 mod 32 uniform), h2 stride 48. LDS 46.6KB -> 10KB.
// MFMA layouts (m89/m120/R16-verified): A[m=lane&15][k=quad*8+j],
// B[k=quad*8+j][n=lane&15], C/D: col(n)=lane&15, row(m)=quad*4+reg.
// h-parity (R8 scheme): at tick t, h1(t-1) in s_h1[(t+1)&1]; GRU2 reads
// h2(t-2) from s_h2[t&1], writes h2(t-1) to s_h2[(t+1)&1]. exp2
// pre-scaled gate math (R10-validated).
__global__ __launch_bounds__(384, 1)
void gru2_encoder(const float* __restrict__ x,
                  const float* __restrict__ W_ih1,
                  const float* __restrict__ W_hh1,
                  const float* __restrict__ b_ih1,
                  const float* __restrict__ b_hh1,
                  const float* __restrict__ W_ih2,
                  const float* __restrict__ W_hh2,
                  const float* __restrict__ b_ih2,
                  const float* __restrict__ b_hh2,
                  float* __restrict__ out)
{
    const int blk  = blockIdx.x;    // 256 blocks, CH=4 chains each
    const int tid  = threadIdx.x;   // 384
    const int lane = tid & 63;
    const int wid  = tid >> 6;      // 0..5
    const int nl   = lane & 15;     // MFMA non-k lane index (unit col)
    const int quad = lane >> 4;     // 0..3 (= this lane's gate CHAIN)
    const int ac   = nl >> 2;       // chain this lane's A-row replicates
    const int chain0 = blk * CH;

    const float SNEG = -1.44269504f;       // -log2(e)
    const float SP2  =  2.88539008f;       // 2*log2(e)

    // strides padded for uniform 2-way bank access (see header comment)
    __shared__ __align__(16) _Float16 s_h1[2][4][80];   // [par][chain][unit64 pad80]
    __shared__ __align__(16) _Float16 s_h2[2][4][48];   // [par][chain][unit32 pad48]
    __shared__ __align__(16) _Float16 s_x[TSTEPS][4];   // x f16, [t][chain]

    // ---- one-time staging
    for (int idx = tid; idx < 4 * TSTEPS; idx += 384) {
        const int m = idx >> 10, t = idx & (TSTEPS - 1);
        s_x[t][m] = (_Float16)x[(size_t)(chain0 + m) * TSTEPS + t];
    }
    {
        _Float16* p1 = &s_h1[0][0][0];
        for (int idx = tid; idx < 2 * 4 * 80; idx += 384) p1[idx] = (_Float16)0.0f;
        _Float16* p2 = &s_h2[0][0][0];
        for (int idx = tid; idx < 2 * 4 * 48; idx += 384) p2[idx] = (_Float16)0.0f;
    }
    __syncthreads();

    if (wid < 4) {
        // ================= GRU1, unit-tile wid: units wid*16+nl =================
        const int un = wid * 16 + nl;        // this lane's output unit (n-col)
        // weights as B operand: B[k=quad*8+jj][n=nl] = W_hh1[un][k] (pre-scaled)
        const half8 Br0 = load_w8s(W_hh1 + (size_t)(un)        * 64 + quad * 8,      SNEG);
        const half8 Br1 = load_w8s(W_hh1 + (size_t)(un)        * 64 + 32 + quad * 8, SNEG);
        const half8 Bz0 = load_w8s(W_hh1 + (size_t)(64 + un)   * 64 + quad * 8,      SNEG);
        const half8 Bz1 = load_w8s(W_hh1 + (size_t)(64 + un)   * 64 + 32 + quad * 8, SNEG);
        const half8 Bn0 = load_w8s(W_hh1 + (size_t)(128 + un)  * 64 + quad * 8,      SP2);
        const half8 Bn1 = load_w8s(W_hh1 + (size_t)(128 + un)  * 64 + 32 + quad * 8, SP2);
        // bias depends on unit (col) only -> splat across the 4 C rows
        const float cr = SNEG * (b_ih1[un] + b_hh1[un]);
        const float cz = SNEG * (b_ih1[64 + un] + b_hh1[64 + un]);
        const float cn = SP2 * b_hh1[128 + un];
        const f32x4 Cr = {cr, cr, cr, cr};
        const f32x4 Cz = {cz, cz, cz, cz};
        const f32x4 Cn = {cn, cn, cn, cn};
        // x-path scalars for this lane's unit
        const float twr = SNEG * W_ih1[un];
        const float twz = SNEG * W_ih1[64 + un];
        const float twn = SP2  * W_ih1[128 + un];
        const float tbn = SP2  * b_ih1[128 + un];

        float h1s = 0.0f;   // h1[chain=quad][unit=un]

        for (int t = 0; t <= TSTEPS; ++t) {
            if (t < TSTEPS) {
                const int pr = (t + 1) & 1;
                // A = h1(t-1), chain replicated over 4 rows: A[m=nl] = h1[nl>>2][k]
                const half8 A0 = *(const half8*)&s_h1[pr][ac][quad * 8];
                const half8 A1 = *(const half8*)&s_h1[pr][ac][32 + quad * 8];
                f32x4 aR = MFMA16(A0, Br0, Cr); aR = MFMA16(A1, Br1, aR);
                f32x4 aZ = MFMA16(A0, Bz0, Cz); aZ = MFMA16(A1, Bz1, aZ);
                f32x4 aN = MFMA16(A0, Bn0, Cn); aN = MFMA16(A1, Bn1, aN);
                // C rows 4*quad..4*quad+3 all equal chain quad -> use reg 0
                const float xv = (float)s_x[t][quad];
                const float ea = fast_exp2(fmaf(twr, xv, aR[0]));   // e^{-ar}
                const float eb = fast_exp2(fmaf(twz, xv, aZ[0]));   // e^{-az}
                const float d1 = 1.0f + ea, d2 = 1.0f + eb;
                const float inv = fast_rcp(d1 * d2);
                const float rg = d2 * inv, zg = d1 * inv;
                const float nx = fmaf(twn, xv, tbn);
                const float ec = fast_exp2(fmaf(rg, aN[0], nx));    // e^{2an}
                const float nn = fmaf(-2.0f, fast_rcp(ec + 1.0f), 1.0f);
                h1s = nn + zg * (h1s - nn);
                s_h1[t & 1][quad][un] = (_Float16)h1s;
            }
            __syncthreads();
        }
    } else {
        // ================= GRU2, units (wid-4)*16+nl, one step behind ==========
        const int vn = (wid - 4) * 16 + nl;  // this lane's output unit (n-col)
        const half8 BiR0 = load_w8s(W_ih2 + (size_t)(vn)      * 64 + quad * 8,      SNEG);
        const half8 BiR1 = load_w8s(W_ih2 + (size_t)(vn)      * 64 + 32 + quad * 8, SNEG);
        const half8 BiZ0 = load_w8s(W_ih2 + (size_t)(32 + vn) * 64 + quad * 8,      SNEG);
        const half8 BiZ1 = load_w8s(W_ih2 + (size_t)(32 + vn) * 64 + 32 + quad * 8, SNEG);
        const half8 BiN0 = load_w8s(W_ih2 + (size_t)(64 + vn) * 64 + quad * 8,      SP2);
        const half8 BiN1 = load_w8s(W_ih2 + (size_t)(64 + vn) * 64 + 32 + quad * 8, SP2);
        const half8 BhR  = load_w8s(W_hh2 + (size_t)(vn)      * 32 + quad * 8,      SNEG);
        const half8 BhZ  = load_w8s(W_hh2 + (size_t)(32 + vn) * 32 + quad * 8,      SNEG);
        const half8 BhN  = load_w8s(W_hh2 + (size_t)(64 + vn) * 32 + quad * 8,      SP2);
        const float gr  = SNEG * (b_ih2[vn] + b_hh2[vn]);
        const float gz  = SNEG * (b_ih2[32 + vn] + b_hh2[32 + vn]);
        const float gnx = SP2 * b_ih2[64 + vn];
        const float gnh = SP2 * b_hh2[64 + vn];
        const f32x4 Gr  = {gr, gr, gr, gr};
        const f32x4 Gz  = {gz, gz, gz, gz};
        const f32x4 Gnx = {gnx, gnx, gnx, gnx};
        const f32x4 Gnh = {gnh, gnh, gnh, gnh};

        float h2s = 0.0f;   // h2[chain=quad][unit=vn]

        for (int t = 0; t <= TSTEPS; ++t) {
            if (t >= 1) {
                const int pA = (t + 1) & 1;            // parity of h1(t-1)
                const half8 A0 = *(const half8*)&s_h1[pA][ac][quad * 8];
                const half8 A1 = *(const half8*)&s_h1[pA][ac][32 + quad * 8];
                const half8 Ah = *(const half8*)&s_h2[t & 1][ac][quad * 8];   // h2(t-2)
                f32x4 aR = MFMA16(A0, BiR0, Gr);  aR = MFMA16(A1, BiR1, aR);
                aR = MFMA16(Ah, BhR, aR);
                f32x4 aZ = MFMA16(A0, BiZ0, Gz);  aZ = MFMA16(A1, BiZ1, aZ);
                aZ = MFMA16(Ah, BhZ, aZ);
                f32x4 aNx = MFMA16(A0, BiN0, Gnx); aNx = MFMA16(A1, BiN1, aNx);
                f32x4 aNh = MFMA16(Ah, BhN, Gnh);
                const float ea = fast_exp2(aR[0]);
                const float eb = fast_exp2(aZ[0]);
                const float d1 = 1.0f + ea, d2 = 1.0f + eb;
                const float inv = fast_rcp(d1 * d2);
                const float rg = d2 * inv, zg = d1 * inv;
                const float ec = fast_exp2(fmaf(rg, aNh[0], aNx[0]));
                const float n2 = fmaf(-2.0f, fast_rcp(ec + 1.0f), 1.0f);
                h2s = n2 + zg * (h2s - n2);
                s_h2[(t + 1) & 1][quad][vn] = (_Float16)h2s;   // h2(t-1)
            }
            __syncthreads();
        }

        // lane holds h2 for (chain=quad, unit=vn): coalesced b32 stores
        out[(size_t)(chain0 + quad) * 32 + vn] = h2s;
    }
}

extern "C" void kernel_launch(void* const* d_in, const int* in_sizes, int n_in,
                              void* d_out, int out_size, void* d_ws, size_t ws_size,
                              hipStream_t stream) {
    const float* x     = (const float*)d_in[0];
    const float* W_ih1 = (const float*)d_in[1];
    const float* W_hh1 = (const float*)d_in[2];
    const float* b_ih1 = (const float*)d_in[3];
    const float* b_hh1 = (const float*)d_in[4];
    const float* W_ih2 = (const float*)d_in[5];
    const float* W_hh2 = (const float*)d_in[6];
    const float* b_ih2 = (const float*)d_in[7];
    const float* b_hh2 = (const float*)d_in[8];
    float* out = (float*)d_out;

    gru2_encoder<<<dim3(1024 / CH), dim3(384), 0, stream>>>(
        x, W_ih1, W_hh1, b_ih1, b_hh1, W_ih2, W_hh2, b_ih2, b_hh2, out);
}